// Round 4
// baseline (459.073 us; speedup 1.0000x reference)
//
#include <hip/hip_runtime.h>
#include <cstddef>
#include <cstdint>

#define BATCH 32

// All intermediates are NODE-MAJOR: X[n][b][f]  (addr = (n*32 + b)*F + f).
// Workspace (floats):
//   Xt : 1,572,864   (transposed input, [16384][32][3])
//   T  : 16,777,216  (T1..T4, max slice = layer1: 4096*32*32 = 4,194,304)
//   X1 : 4,194,304   ([4096][32][32])
//   X2 : 1,048,576   ([1024][32][32])
//   X3 : 262,144     ([256][32][32])
//   X4 : 131,072     ([32][4096] BATCH-major for encoder)
//   P  : 65,536      (encoder split-K partials)

__device__ __forceinline__ void fma4(float4& a, float s, const float4& w) {
  a.x += s * w.x; a.y += s * w.y; a.z += s * w.z; a.w += s * w.w;
}
__device__ __forceinline__ float4 relu4(const float4& a) {
  return make_float4(fmaxf(a.x, 0.f), fmaxf(a.y, 0.f), fmaxf(a.z, 0.f), fmaxf(a.w, 0.f));
}

// ---------------- transpose x[b][n][3] -> Xt[n][b][3] ----------------
__global__ void __launch_bounds__(256) transpose_x(
    const float* __restrict__ x, float* __restrict__ xt)
{
  int t = blockIdx.x * 256 + threadIdx.x;     // n*96 + b*3 + f
  int n = t / 96;
  int r = t % 96;
  int b = r / 3;
  int f = r - b * 3;
  xt[t] = x[((size_t)b * 16384 + n) * 3 + f];
}

// ---------------- node-major Cheb step ----------------
// out[n][r] = coef * sum_{d<6} in[ec[n,d]][r] + beta * pp[n][r]   (r over B*F/4 float4s)
template<int N, int R4>
__global__ void __launch_bounds__(256) cheb_step_nm(
    const float4* __restrict__ Tin, const float4* __restrict__ Tpp,
    const int* __restrict__ ec, float4* __restrict__ Tout,
    float coef, float beta)
{
  int idx = blockIdx.x * 256 + threadIdx.x;   // exact grid: N*R4 threads
  int n = idx / R4;
  int r = idx % R4;
  const int* e = ec + n * 6;
  float4 s = make_float4(0.f, 0.f, 0.f, 0.f);
#pragma unroll
  for (int d = 0; d < 6; ++d) {
    float4 v = Tin[(size_t)e[d] * R4 + r];
    s.x += v.x; s.y += v.y; s.z += v.z; s.w += v.w;
  }
  float4 p = Tpp[idx];
  float4 o;
  o.x = coef * s.x + beta * p.x;
  o.y = coef * s.y + beta * p.y;
  o.z = coef * s.z + beta * p.z;
  o.w = coef * s.w + beta * p.w;
  Tout[idx] = o;
}

// ---------------- fused pool(relu(conv)), FIN=3, inline T5 ----------------
// T holds T1..T4 only; T5[c] = cS*G(T4)[c] - T3[c] computed at gather points.
template<int N, int M, int FOUT, bool OUT_BM>
__global__ void __launch_bounds__(256) pool_conv_f3(
    const float* __restrict__ X, const float* __restrict__ T,
    const int* __restrict__ ec,
    const float* __restrict__ W, const float* __restrict__ bias,
    const int* __restrict__ pc, const float* __restrict__ pv,
    float* __restrict__ out)
{
  constexpr int F4 = FOUT / 4;
  constexpr size_t SL = (size_t)N * BATCH * 3;
  __shared__ float Ws[6 * 3 * FOUT];
  for (int i = threadIdx.x; i < 6 * 3 * FOUT; i += 256) Ws[i] = W[i];
  __syncthreads();
  const float4* Ws4 = (const float4*)Ws;
  int t = blockIdx.x * 256 + threadIdx.x;     // exact grid: M*32*F4
  int fo4 = t % F4;
  int b   = (t / F4) % BATCH;
  int m   = t / (F4 * BATCH);
  int c[3]; float pw[3];
#pragma unroll
  for (int j = 0; j < 3; ++j) { c[j] = pc[m * 3 + j]; pw[j] = pv[m * 3 + j]; }
  float4 bi = ((const float4*)bias)[fo4];
  float4 a0 = bi, a1 = bi, a2 = bi;
#pragma unroll
  for (int k = 0; k < 5; ++k) {
    const float* base = (k == 0) ? X : (T + (size_t)(k - 1) * SL);
    const float* r0 = base + ((size_t)c[0] * BATCH + b) * 3;
    const float* r1 = base + ((size_t)c[1] * BATCH + b) * 3;
    const float* r2 = base + ((size_t)c[2] * BATCH + b) * 3;
#pragma unroll
    for (int f = 0; f < 3; ++f) {
      float4 w = Ws4[(k * 3 + f) * F4 + fo4];
      fma4(a0, r0[f], w);
      fma4(a1, r1[f], w);
      fma4(a2, r2[f], w);
    }
  }
  // k = 5 inline
  const float cS = -1.f / 3.f;
  float4* accs[3] = {&a0, &a1, &a2};
#pragma unroll
  for (int j = 0; j < 3; ++j) {
    const int* e = ec + c[j] * 6;
    const float* t4 = T + 3 * SL;
    const float* t3row = T + 2 * SL + ((size_t)c[j] * BATCH + b) * 3;
    float s0 = 0.f, s1 = 0.f, s2 = 0.f;
#pragma unroll
    for (int d = 0; d < 6; ++d) {
      const float* rr = t4 + ((size_t)e[d] * BATCH + b) * 3;
      s0 += rr[0]; s1 += rr[1]; s2 += rr[2];
    }
    float t5[3] = {cS * s0 - t3row[0], cS * s1 - t3row[1], cS * s2 - t3row[2]};
#pragma unroll
    for (int f = 0; f < 3; ++f) {
      float4 w = Ws4[(5 * 3 + f) * F4 + fo4];
      fma4(*accs[j], t5[f], w);
    }
  }
  a0 = relu4(a0); a1 = relu4(a1); a2 = relu4(a2);
  float4 acc;
  acc.x = pw[0]*a0.x + pw[1]*a1.x + pw[2]*a2.x;
  acc.y = pw[0]*a0.y + pw[1]*a1.y + pw[2]*a2.y;
  acc.z = pw[0]*a0.z + pw[1]*a1.z + pw[2]*a2.z;
  acc.w = pw[0]*a0.w + pw[1]*a1.w + pw[2]*a2.w;
  size_t oi = OUT_BM ? (((size_t)b * M + m) * F4 + fo4) : (((size_t)m * BATCH + b) * F4 + fo4);
  ((float4*)out)[oi] = acc;
}

// ---------------- fused pool(relu(conv)), FIN=32, inline T5 ----------------
template<int N, int M, int FOUT, bool OUT_BM>
__global__ void __launch_bounds__(256) pool_conv_v32(
    const float* __restrict__ X, const float* __restrict__ T,
    const int* __restrict__ ec,
    const float* __restrict__ W, const float* __restrict__ bias,
    const int* __restrict__ pc, const float* __restrict__ pv,
    float* __restrict__ out)
{
  constexpr int FIN = 32;
  constexpr int F4 = FOUT / 4;
  constexpr size_t SL4 = (size_t)N * BATCH * FIN / 4;   // slice stride in float4
  __shared__ float Ws[6 * FIN * FOUT];                  // 24 KB or 48 KB
  for (int i = threadIdx.x; i < 6 * FIN * FOUT; i += 256) Ws[i] = W[i];
  __syncthreads();
  const float4* Ws4 = (const float4*)Ws;
  const float4* X4 = (const float4*)X;
  const float4* T4s = (const float4*)T;
  int t = blockIdx.x * 256 + threadIdx.x;     // exact grid: M*32*F4
  int fo4 = t % F4;
  int b   = (t / F4) % BATCH;
  int m   = t / (F4 * BATCH);
  int c[3]; float pw[3];
#pragma unroll
  for (int j = 0; j < 3; ++j) { c[j] = pc[m * 3 + j]; pw[j] = pv[m * 3 + j]; }
  float4 bi = ((const float4*)bias)[fo4];
  float4 a0 = bi, a1 = bi, a2 = bi;
  // k = 0 from X
  {
    const float4* r0 = X4 + ((size_t)c[0] * BATCH + b) * 8;
    const float4* r1 = X4 + ((size_t)c[1] * BATCH + b) * 8;
    const float4* r2 = X4 + ((size_t)c[2] * BATCH + b) * 8;
#pragma unroll
    for (int fi = 0; fi < 8; ++fi) {
      float4 t0 = r0[fi], t1 = r1[fi], t2 = r2[fi];
#pragma unroll
      for (int ff = 0; ff < 4; ++ff) {
        float4 w = Ws4[(fi * 4 + ff) * F4 + fo4];
        fma4(a0, ((const float*)&t0)[ff], w);
        fma4(a1, ((const float*)&t1)[ff], w);
        fma4(a2, ((const float*)&t2)[ff], w);
      }
    }
  }
  // k = 1..4 from T slices
#pragma unroll 1
  for (int k = 1; k < 5; ++k) {
    const float4* base = T4s + (size_t)(k - 1) * SL4;
    const float4* r0 = base + ((size_t)c[0] * BATCH + b) * 8;
    const float4* r1 = base + ((size_t)c[1] * BATCH + b) * 8;
    const float4* r2 = base + ((size_t)c[2] * BATCH + b) * 8;
#pragma unroll
    for (int fi = 0; fi < 8; ++fi) {
      float4 t0 = r0[fi], t1 = r1[fi], t2 = r2[fi];
#pragma unroll
      for (int ff = 0; ff < 4; ++ff) {
        float4 w = Ws4[((k * 32) + fi * 4 + ff) * F4 + fo4];
        fma4(a0, ((const float*)&t0)[ff], w);
        fma4(a1, ((const float*)&t1)[ff], w);
        fma4(a2, ((const float*)&t2)[ff], w);
      }
    }
  }
  // k = 5 inline: T5[c] = cS * G(T4)[c] - T3[c]
  const float cS = -1.f / 3.f;
  float4* accs[3] = {&a0, &a1, &a2};
#pragma unroll 1
  for (int j = 0; j < 3; ++j) {
    const int* e = ec + c[j] * 6;
    const float4* t4 = T4s + 3 * SL4;
    const float4* t3row = T4s + 2 * SL4 + ((size_t)c[j] * BATCH + b) * 8;
    int e0 = e[0], e1 = e[1], e2 = e[2], e3 = e[3], e4 = e[4], e5 = e[5];
    const float4* g0 = t4 + ((size_t)e0 * BATCH + b) * 8;
    const float4* g1 = t4 + ((size_t)e1 * BATCH + b) * 8;
    const float4* g2 = t4 + ((size_t)e2 * BATCH + b) * 8;
    const float4* g3 = t4 + ((size_t)e3 * BATCH + b) * 8;
    const float4* g4 = t4 + ((size_t)e4 * BATCH + b) * 8;
    const float4* g5 = t4 + ((size_t)e5 * BATCH + b) * 8;
#pragma unroll
    for (int fi = 0; fi < 8; ++fi) {
      float4 v0 = g0[fi], v1 = g1[fi], v2 = g2[fi];
      float4 v3 = g3[fi], v4 = g4[fi], v5 = g5[fi];
      float4 t3v = t3row[fi];
      float4 t5;
      t5.x = cS * (v0.x+v1.x+v2.x+v3.x+v4.x+v5.x) - t3v.x;
      t5.y = cS * (v0.y+v1.y+v2.y+v3.y+v4.y+v5.y) - t3v.y;
      t5.z = cS * (v0.z+v1.z+v2.z+v3.z+v4.z+v5.z) - t3v.z;
      t5.w = cS * (v0.w+v1.w+v2.w+v3.w+v4.w+v5.w) - t3v.w;
#pragma unroll
      for (int ff = 0; ff < 4; ++ff) {
        float4 w = Ws4[((5 * 32) + fi * 4 + ff) * F4 + fo4];
        fma4(*accs[j], ((const float*)&t5)[ff], w);
      }
    }
  }
  a0 = relu4(a0); a1 = relu4(a1); a2 = relu4(a2);
  float4 acc;
  acc.x = pw[0]*a0.x + pw[1]*a1.x + pw[2]*a2.x;
  acc.y = pw[0]*a0.y + pw[1]*a1.y + pw[2]*a2.y;
  acc.z = pw[0]*a0.z + pw[1]*a1.z + pw[2]*a2.z;
  acc.w = pw[0]*a0.w + pw[1]*a1.w + pw[2]*a2.w;
  size_t oi = OUT_BM ? (((size_t)b * M + m) * F4 + fo4) : (((size_t)m * BATCH + b) * F4 + fo4);
  ((float4*)out)[oi] = acc;
}

// ---------------- encoder split-K partial ----------------
__global__ void __launch_bounds__(256) encoder_partial(
    const float* __restrict__ Xf, const float* __restrict__ encW,
    float* __restrict__ partial)
{
  int b  = blockIdx.x;        // 0..31
  int ks = blockIdx.y;        // 0..15
  int fo = threadIdx.x & 127;
  int half = threadIdx.x >> 7;
  const float* xr = Xf + b * 4096 + ks * 256 + half * 128;
  const float* w  = encW + (size_t)(ks * 256 + half * 128) * 128;
  float acc = 0.f;
#pragma unroll 8
  for (int i = 0; i < 128; ++i) acc += xr[i] * w[(size_t)i * 128 + fo];
  __shared__ float part[256];
  part[threadIdx.x] = acc;
  __syncthreads();
  if (half == 0) partial[(size_t)(b * 16 + ks) * 128 + fo] = part[fo] + part[128 + fo];
}

// ---------------- fused encoder-reduce + relu + classifier ----------------
__global__ void __launch_bounds__(128) encoder_reduce_cls(
    const float* __restrict__ partial, const float* __restrict__ encB,
    const float* __restrict__ clsW, const float* __restrict__ clsB,
    float* __restrict__ out)
{
  int b = blockIdx.x;           // 0..31
  int fo = threadIdx.x;         // 0..127
  float acc = encB[fo];
#pragma unroll
  for (int ks = 0; ks < 16; ++ks) acc += partial[(size_t)(b * 16 + ks) * 128 + fo];
  __shared__ float Hs[128];
  Hs[fo] = fmaxf(acc, 0.f);
  __syncthreads();
  if (fo < 10) {
    float s = clsB[fo];
#pragma unroll 4
    for (int f = 0; f < 128; ++f) s += Hs[f] * clsW[f * 10 + fo];
    out[b * 10 + fo] = s;
  }
}

extern "C" void kernel_launch(void* const* d_in, const int* in_sizes, int n_in,
                              void* d_out, int out_size, void* d_ws, size_t ws_size,
                              hipStream_t stream)
{
  const float* x   = (const float*)d_in[0];
  const int* ec0 = (const int*)d_in[2];
  const int* ec1 = (const int*)d_in[4];
  const int* ec2 = (const int*)d_in[6];
  const int* ec3 = (const int*)d_in[8];
  const int* pc0 = (const int*)d_in[10]; const float* pv0 = (const float*)d_in[11];
  const int* pc1 = (const int*)d_in[13]; const float* pv1 = (const float*)d_in[14];
  const int* pc2 = (const int*)d_in[16]; const float* pv2 = (const float*)d_in[17];
  const int* pc3 = (const int*)d_in[19]; const float* pv3 = (const float*)d_in[20];
  const float* W0 = (const float*)d_in[21]; const float* b0 = (const float*)d_in[22];
  const float* W1 = (const float*)d_in[23]; const float* b1 = (const float*)d_in[24];
  const float* W2 = (const float*)d_in[25]; const float* b2 = (const float*)d_in[26];
  const float* W3 = (const float*)d_in[27]; const float* b3 = (const float*)d_in[28];
  const float* encW = (const float*)d_in[29]; const float* encB = (const float*)d_in[30];
  const float* clsW = (const float*)d_in[31]; const float* clsB = (const float*)d_in[32];
  float* out = (float*)d_out;

  float* ws = (float*)d_ws;
  float* Xt = ws;                       // 1,572,864
  float* T  = Xt + 1572864;             // 16,777,216 (T1..T4, layer-1 sized)
  float* X1 = T  + 16777216;            // 4,194,304
  float* X2 = X1 + 4194304;             // 1,048,576
  float* X3 = X2 + 1048576;             // 262,144
  float* X4 = X3 + 262144;              // 131,072  ([32][4096])
  float* P  = X4 + 131072;              // 65,536

  const float cI = -1.0f / 6.0f;
  const float cS = -1.0f / 3.0f;
  dim3 blk(256);

  transpose_x<<<dim3(6144), blk, 0, stream>>>(x, Xt);

  // ================= layer 0: N=16384, R=96 (R4=24), M=4096 =================
  {
    constexpr size_t S = (size_t)16384 * 96;   // slice floats
    const float4* Xt4 = (const float4*)Xt;
    cheb_step_nm<16384, 24><<<dim3(1536), blk, 0, stream>>>(
        Xt4, Xt4, ec0, (float4*)T, cI, 0.f);
    cheb_step_nm<16384, 24><<<dim3(1536), blk, 0, stream>>>(
        (const float4*)T, Xt4, ec0, (float4*)(T + S), cS, -1.f);
    cheb_step_nm<16384, 24><<<dim3(1536), blk, 0, stream>>>(
        (const float4*)(T + S), (const float4*)T, ec0, (float4*)(T + 2 * S), cS, -1.f);
    cheb_step_nm<16384, 24><<<dim3(1536), blk, 0, stream>>>(
        (const float4*)(T + 2 * S), (const float4*)(T + S), ec0, (float4*)(T + 3 * S), cS, -1.f);
    pool_conv_f3<16384, 4096, 32, false><<<dim3(4096), blk, 0, stream>>>(
        Xt, T, ec0, W0, b0, pc0, pv0, X1);
  }
  // ================= layer 1: N=4096, R=1024 (R4=256), M=1024 =================
  {
    constexpr size_t S = (size_t)4096 * 1024;
    const float4* X14 = (const float4*)X1;
    cheb_step_nm<4096, 256><<<dim3(4096), blk, 0, stream>>>(
        X14, X14, ec1, (float4*)T, cI, 0.f);
    cheb_step_nm<4096, 256><<<dim3(4096), blk, 0, stream>>>(
        (const float4*)T, X14, ec1, (float4*)(T + S), cS, -1.f);
    cheb_step_nm<4096, 256><<<dim3(4096), blk, 0, stream>>>(
        (const float4*)(T + S), (const float4*)T, ec1, (float4*)(T + 2 * S), cS, -1.f);
    cheb_step_nm<4096, 256><<<dim3(4096), blk, 0, stream>>>(
        (const float4*)(T + 2 * S), (const float4*)(T + S), ec1, (float4*)(T + 3 * S), cS, -1.f);
    pool_conv_v32<4096, 1024, 32, false><<<dim3(1024), blk, 0, stream>>>(
        X1, T, ec1, W1, b1, pc1, pv1, X2);
  }
  // ================= layer 2: N=1024, M=256 =================
  {
    constexpr size_t S = (size_t)1024 * 1024;
    const float4* X24 = (const float4*)X2;
    cheb_step_nm<1024, 256><<<dim3(1024), blk, 0, stream>>>(
        X24, X24, ec2, (float4*)T, cI, 0.f);
    cheb_step_nm<1024, 256><<<dim3(1024), blk, 0, stream>>>(
        (const float4*)T, X24, ec2, (float4*)(T + S), cS, -1.f);
    cheb_step_nm<1024, 256><<<dim3(1024), blk, 0, stream>>>(
        (const float4*)(T + S), (const float4*)T, ec2, (float4*)(T + 2 * S), cS, -1.f);
    cheb_step_nm<1024, 256><<<dim3(1024), blk, 0, stream>>>(
        (const float4*)(T + 2 * S), (const float4*)(T + S), ec2, (float4*)(T + 3 * S), cS, -1.f);
    pool_conv_v32<1024, 256, 32, false><<<dim3(256), blk, 0, stream>>>(
        X2, T, ec2, W2, b2, pc2, pv2, X3);
  }
  // ================= layer 3: N=256, M=64, FOUT=64, batch-major out =================
  {
    constexpr size_t S = (size_t)256 * 1024;
    const float4* X34 = (const float4*)X3;
    cheb_step_nm<256, 256><<<dim3(256), blk, 0, stream>>>(
        X34, X34, ec3, (float4*)T, cI, 0.f);
    cheb_step_nm<256, 256><<<dim3(256), blk, 0, stream>>>(
        (const float4*)T, X34, ec3, (float4*)(T + S), cS, -1.f);
    cheb_step_nm<256, 256><<<dim3(256), blk, 0, stream>>>(
        (const float4*)(T + S), (const float4*)T, ec3, (float4*)(T + 2 * S), cS, -1.f);
    cheb_step_nm<256, 256><<<dim3(256), blk, 0, stream>>>(
        (const float4*)(T + 2 * S), (const float4*)(T + S), ec3, (float4*)(T + 3 * S), cS, -1.f);
    pool_conv_v32<256, 64, 64, true><<<dim3(128), blk, 0, stream>>>(
        X3, T, ec3, W3, b3, pc3, pv3, X4);
  }
  // ================= head =================
  encoder_partial<<<dim3(32, 16), blk, 0, stream>>>(X4, encW, P);
  encoder_reduce_cls<<<dim3(32), dim3(128), 0, stream>>>(P, encB, clsW, clsB, out);
}

// Round 5
// 362.846 us; speedup vs baseline: 1.2652x; 1.2652x over previous
//
#include <hip/hip_runtime.h>
#include <cstddef>
#include <cstdint>

#define BATCH 32

// All intermediates are NODE-MAJOR: X[n][b][f]  (addr = (n*32 + b)*F + f).
// Workspace (floats):
//   Xt : 1,572,864   (transposed input, [16384][32][3])
//   T  : 20,971,520  (T1..T5; max slice = layer1: 4096*32*32 = 4,194,304)
//   X1 : 4,194,304   ([4096][32][32])
//   X2 : 1,048,576   ([1024][32][32])
//   X3 : 262,144     ([256][32][32])
//   X4 : 131,072     ([32][4096] BATCH-major for encoder)
//   P  : 65,536      (encoder split-K partials)

__device__ __forceinline__ void fma4(float4& a, float s, const float4& w) {
  a.x += s * w.x; a.y += s * w.y; a.z += s * w.z; a.w += s * w.w;
}
__device__ __forceinline__ float4 relu4(const float4& a) {
  return make_float4(fmaxf(a.x, 0.f), fmaxf(a.y, 0.f), fmaxf(a.z, 0.f), fmaxf(a.w, 0.f));
}

// ---------------- transpose x[b][n][3] -> Xt[n][b][3] ----------------
__global__ void __launch_bounds__(256) transpose_x(
    const float* __restrict__ x, float* __restrict__ xt)
{
  int t = blockIdx.x * 256 + threadIdx.x;     // n*96 + b*3 + f
  int n = t / 96;
  int r = t % 96;
  int b = r / 3;
  int f = r - b * 3;
  xt[t] = x[((size_t)b * 16384 + n) * 3 + f];
}

// ---------------- node-major Cheb step ----------------
// out[n][r] = coef * sum_{d<6} in[ec[n,d]][r] + beta * pp[n][r]   (r over B*F/4 float4s)
template<int N, int R4>
__global__ void __launch_bounds__(256) cheb_step_nm(
    const float4* __restrict__ Tin, const float4* __restrict__ Tpp,
    const int* __restrict__ ec, float4* __restrict__ Tout,
    float coef, float beta)
{
  int idx = blockIdx.x * 256 + threadIdx.x;   // exact grid: N*R4 threads
  int n = idx / R4;
  int r = idx % R4;
  const int* e = ec + n * 6;
  float4 s = make_float4(0.f, 0.f, 0.f, 0.f);
#pragma unroll
  for (int d = 0; d < 6; ++d) {
    float4 v = Tin[(size_t)e[d] * R4 + r];
    s.x += v.x; s.y += v.y; s.z += v.z; s.w += v.w;
  }
  float4 p = Tpp[idx];
  float4 o;
  o.x = coef * s.x + beta * p.x;
  o.y = coef * s.y + beta * p.y;
  o.z = coef * s.z + beta * p.z;
  o.w = coef * s.w + beta * p.w;
  Tout[idx] = o;
}

// ---------------- fused pool(relu(conv)), FIN=3, materialized T1..T5 ----------------
// out[m,b,fo] (or [b,m,fo]) = sum_j pv[3m+j] * relu(bias + sum_k T_k[pc[3m+j]][b][:] W[k])
template<int N, int M, int FOUT, bool OUT_BM>
__global__ void __launch_bounds__(256) pool_conv_f3(
    const float* __restrict__ X, const float* __restrict__ T,
    const float* __restrict__ W, const float* __restrict__ bias,
    const int* __restrict__ pc, const float* __restrict__ pv,
    float* __restrict__ out)
{
  constexpr int F4 = FOUT / 4;
  constexpr size_t SL = (size_t)N * BATCH * 3;   // slice stride (floats)
  __shared__ float Ws[6 * 3 * FOUT];
  for (int i = threadIdx.x; i < 6 * 3 * FOUT; i += 256) Ws[i] = W[i];
  __syncthreads();
  const float4* Ws4 = (const float4*)Ws;
  int t = blockIdx.x * 256 + threadIdx.x;     // exact grid: M*32*F4
  int fo4 = t % F4;
  int b   = (t / F4) % BATCH;
  int m   = t / (F4 * BATCH);
  int c0 = pc[m * 3 + 0], c1 = pc[m * 3 + 1], c2 = pc[m * 3 + 2];
  float v0 = pv[m * 3 + 0], v1 = pv[m * 3 + 1], v2 = pv[m * 3 + 2];
  float4 bi = ((const float4*)bias)[fo4];
  float4 a0 = bi, a1 = bi, a2 = bi;
#pragma unroll
  for (int k = 0; k < 6; ++k) {
    const float* base = (k == 0) ? X : (T + (size_t)(k - 1) * SL);
    const float* r0 = base + ((size_t)c0 * BATCH + b) * 3;
    const float* r1 = base + ((size_t)c1 * BATCH + b) * 3;
    const float* r2 = base + ((size_t)c2 * BATCH + b) * 3;
#pragma unroll
    for (int f = 0; f < 3; ++f) {
      float4 w = Ws4[(k * 3 + f) * F4 + fo4];
      fma4(a0, r0[f], w);
      fma4(a1, r1[f], w);
      fma4(a2, r2[f], w);
    }
  }
  a0 = relu4(a0); a1 = relu4(a1); a2 = relu4(a2);
  float4 acc;
  acc.x = v0*a0.x + v1*a1.x + v2*a2.x;
  acc.y = v0*a0.y + v1*a1.y + v2*a2.y;
  acc.z = v0*a0.z + v1*a1.z + v2*a2.z;
  acc.w = v0*a0.w + v1*a1.w + v2*a2.w;
  size_t oi = OUT_BM ? (((size_t)b * M + m) * F4 + fo4) : (((size_t)m * BATCH + b) * F4 + fo4);
  ((float4*)out)[oi] = acc;
}

// ---------------- fused pool(relu(conv)), FIN=32, materialized T1..T5 ----------------
template<int N, int M, int FOUT, bool OUT_BM>
__global__ void __launch_bounds__(256) pool_conv_v32(
    const float* __restrict__ X, const float* __restrict__ T,
    const float* __restrict__ W, const float* __restrict__ bias,
    const int* __restrict__ pc, const float* __restrict__ pv,
    float* __restrict__ out)
{
  constexpr int FIN = 32;
  constexpr int F4 = FOUT / 4;
  constexpr size_t SL4 = (size_t)N * BATCH * FIN / 4;   // slice stride (float4)
  __shared__ float Ws[6 * FIN * FOUT];                  // 24 KB or 48 KB
  for (int i = threadIdx.x; i < 6 * FIN * FOUT; i += 256) Ws[i] = W[i];
  __syncthreads();
  const float4* Ws4 = (const float4*)Ws;
  const float4* X4p = (const float4*)X;
  const float4* T4s = (const float4*)T;
  int t = blockIdx.x * 256 + threadIdx.x;     // exact grid: M*32*F4
  int fo4 = t % F4;
  int b   = (t / F4) % BATCH;
  int m   = t / (F4 * BATCH);
  int c0 = pc[m * 3 + 0], c1 = pc[m * 3 + 1], c2 = pc[m * 3 + 2];
  float v0 = pv[m * 3 + 0], v1 = pv[m * 3 + 1], v2 = pv[m * 3 + 2];
  float4 bi = ((const float4*)bias)[fo4];
  float4 a0 = bi, a1 = bi, a2 = bi;
#pragma unroll 1
  for (int k = 0; k < 6; ++k) {
    const float4* base = (k == 0) ? X4p : (T4s + (size_t)(k - 1) * SL4);
    const float4* r0 = base + ((size_t)c0 * BATCH + b) * 8;
    const float4* r1 = base + ((size_t)c1 * BATCH + b) * 8;
    const float4* r2 = base + ((size_t)c2 * BATCH + b) * 8;
#pragma unroll
    for (int fi = 0; fi < 8; ++fi) {
      float4 t0 = r0[fi], t1 = r1[fi], t2 = r2[fi];
#pragma unroll
      for (int ff = 0; ff < 4; ++ff) {
        float4 w = Ws4[((k * 32) + fi * 4 + ff) * F4 + fo4];
        fma4(a0, ((const float*)&t0)[ff], w);
        fma4(a1, ((const float*)&t1)[ff], w);
        fma4(a2, ((const float*)&t2)[ff], w);
      }
    }
  }
  a0 = relu4(a0); a1 = relu4(a1); a2 = relu4(a2);
  float4 acc;
  acc.x = v0*a0.x + v1*a1.x + v2*a2.x;
  acc.y = v0*a0.y + v1*a1.y + v2*a2.y;
  acc.z = v0*a0.z + v1*a1.z + v2*a2.z;
  acc.w = v0*a0.w + v1*a1.w + v2*a2.w;
  size_t oi = OUT_BM ? (((size_t)b * M + m) * F4 + fo4) : (((size_t)m * BATCH + b) * F4 + fo4);
  ((float4*)out)[oi] = acc;
}

// ---------------- encoder split-K partial ----------------
__global__ void __launch_bounds__(256) encoder_partial(
    const float* __restrict__ Xf, const float* __restrict__ encW,
    float* __restrict__ partial)
{
  int b  = blockIdx.x;        // 0..31
  int ks = blockIdx.y;        // 0..15
  int fo = threadIdx.x & 127;
  int half = threadIdx.x >> 7;
  const float* xr = Xf + b * 4096 + ks * 256 + half * 128;
  const float* w  = encW + (size_t)(ks * 256 + half * 128) * 128;
  float acc = 0.f;
#pragma unroll 8
  for (int i = 0; i < 128; ++i) acc += xr[i] * w[(size_t)i * 128 + fo];
  __shared__ float part[256];
  part[threadIdx.x] = acc;
  __syncthreads();
  if (half == 0) partial[(size_t)(b * 16 + ks) * 128 + fo] = part[fo] + part[128 + fo];
}

// ---------------- fused encoder-reduce + relu + classifier ----------------
__global__ void __launch_bounds__(128) encoder_reduce_cls(
    const float* __restrict__ partial, const float* __restrict__ encB,
    const float* __restrict__ clsW, const float* __restrict__ clsB,
    float* __restrict__ out)
{
  int b = blockIdx.x;           // 0..31
  int fo = threadIdx.x;         // 0..127
  float acc = encB[fo];
#pragma unroll
  for (int ks = 0; ks < 16; ++ks) acc += partial[(size_t)(b * 16 + ks) * 128 + fo];
  __shared__ float Hs[128];
  Hs[fo] = fmaxf(acc, 0.f);
  __syncthreads();
  if (fo < 10) {
    float s = clsB[fo];
#pragma unroll 4
    for (int f = 0; f < 128; ++f) s += Hs[f] * clsW[f * 10 + fo];
    out[b * 10 + fo] = s;
  }
}

extern "C" void kernel_launch(void* const* d_in, const int* in_sizes, int n_in,
                              void* d_out, int out_size, void* d_ws, size_t ws_size,
                              hipStream_t stream)
{
  const float* x   = (const float*)d_in[0];
  const int* ec0 = (const int*)d_in[2];
  const int* ec1 = (const int*)d_in[4];
  const int* ec2 = (const int*)d_in[6];
  const int* ec3 = (const int*)d_in[8];
  const int* pc0 = (const int*)d_in[10]; const float* pv0 = (const float*)d_in[11];
  const int* pc1 = (const int*)d_in[13]; const float* pv1 = (const float*)d_in[14];
  const int* pc2 = (const int*)d_in[16]; const float* pv2 = (const float*)d_in[17];
  const int* pc3 = (const int*)d_in[19]; const float* pv3 = (const float*)d_in[20];
  const float* W0 = (const float*)d_in[21]; const float* b0 = (const float*)d_in[22];
  const float* W1 = (const float*)d_in[23]; const float* b1 = (const float*)d_in[24];
  const float* W2 = (const float*)d_in[25]; const float* b2 = (const float*)d_in[26];
  const float* W3 = (const float*)d_in[27]; const float* b3 = (const float*)d_in[28];
  const float* encW = (const float*)d_in[29]; const float* encB = (const float*)d_in[30];
  const float* clsW = (const float*)d_in[31]; const float* clsB = (const float*)d_in[32];
  float* out = (float*)d_out;

  float* ws = (float*)d_ws;
  float* Xt = ws;                       // 1,572,864
  float* T  = Xt + 1572864;             // 20,971,520 (T1..T5, layer-1 sized)
  float* X1 = T  + 20971520;            // 4,194,304
  float* X2 = X1 + 4194304;             // 1,048,576
  float* X3 = X2 + 1048576;             // 262,144
  float* X4 = X3 + 262144;              // 131,072  ([32][4096])
  float* P  = X4 + 131072;              // 65,536

  const float cI = -1.0f / 6.0f;
  const float cS = -1.0f / 3.0f;
  dim3 blk(256);

  transpose_x<<<dim3(6144), blk, 0, stream>>>(x, Xt);

  // ================= layer 0: N=16384, R=96 (R4=24), M=4096 =================
  {
    constexpr size_t S = (size_t)16384 * 96;   // slice floats
    const float4* Xt4 = (const float4*)Xt;
    cheb_step_nm<16384, 24><<<dim3(1536), blk, 0, stream>>>(
        Xt4, Xt4, ec0, (float4*)T, cI, 0.f);
    cheb_step_nm<16384, 24><<<dim3(1536), blk, 0, stream>>>(
        (const float4*)T, Xt4, ec0, (float4*)(T + S), cS, -1.f);
    cheb_step_nm<16384, 24><<<dim3(1536), blk, 0, stream>>>(
        (const float4*)(T + S), (const float4*)T, ec0, (float4*)(T + 2 * S), cS, -1.f);
    cheb_step_nm<16384, 24><<<dim3(1536), blk, 0, stream>>>(
        (const float4*)(T + 2 * S), (const float4*)(T + S), ec0, (float4*)(T + 3 * S), cS, -1.f);
    cheb_step_nm<16384, 24><<<dim3(1536), blk, 0, stream>>>(
        (const float4*)(T + 3 * S), (const float4*)(T + 2 * S), ec0, (float4*)(T + 4 * S), cS, -1.f);
    pool_conv_f3<16384, 4096, 32, false><<<dim3(4096), blk, 0, stream>>>(
        Xt, T, W0, b0, pc0, pv0, X1);
  }
  // ================= layer 1: N=4096, R=1024 (R4=256), M=1024 =================
  {
    constexpr size_t S = (size_t)4096 * 1024;
    const float4* X14 = (const float4*)X1;
    cheb_step_nm<4096, 256><<<dim3(4096), blk, 0, stream>>>(
        X14, X14, ec1, (float4*)T, cI, 0.f);
    cheb_step_nm<4096, 256><<<dim3(4096), blk, 0, stream>>>(
        (const float4*)T, X14, ec1, (float4*)(T + S), cS, -1.f);
    cheb_step_nm<4096, 256><<<dim3(4096), blk, 0, stream>>>(
        (const float4*)(T + S), (const float4*)T, ec1, (float4*)(T + 2 * S), cS, -1.f);
    cheb_step_nm<4096, 256><<<dim3(4096), blk, 0, stream>>>(
        (const float4*)(T + 2 * S), (const float4*)(T + S), ec1, (float4*)(T + 3 * S), cS, -1.f);
    cheb_step_nm<4096, 256><<<dim3(4096), blk, 0, stream>>>(
        (const float4*)(T + 3 * S), (const float4*)(T + 2 * S), ec1, (float4*)(T + 4 * S), cS, -1.f);
    pool_conv_v32<4096, 1024, 32, false><<<dim3(1024), blk, 0, stream>>>(
        X1, T, W1, b1, pc1, pv1, X2);
  }
  // ================= layer 2: N=1024, M=256 =================
  {
    constexpr size_t S = (size_t)1024 * 1024;
    const float4* X24 = (const float4*)X2;
    cheb_step_nm<1024, 256><<<dim3(1024), blk, 0, stream>>>(
        X24, X24, ec2, (float4*)T, cI, 0.f);
    cheb_step_nm<1024, 256><<<dim3(1024), blk, 0, stream>>>(
        (const float4*)T, X24, ec2, (float4*)(T + S), cS, -1.f);
    cheb_step_nm<1024, 256><<<dim3(1024), blk, 0, stream>>>(
        (const float4*)(T + S), (const float4*)T, ec2, (float4*)(T + 2 * S), cS, -1.f);
    cheb_step_nm<1024, 256><<<dim3(1024), blk, 0, stream>>>(
        (const float4*)(T + 2 * S), (const float4*)(T + S), ec2, (float4*)(T + 3 * S), cS, -1.f);
    cheb_step_nm<1024, 256><<<dim3(1024), blk, 0, stream>>>(
        (const float4*)(T + 3 * S), (const float4*)(T + 2 * S), ec2, (float4*)(T + 4 * S), cS, -1.f);
    pool_conv_v32<1024, 256, 32, false><<<dim3(256), blk, 0, stream>>>(
        X2, T, W2, b2, pc2, pv2, X3);
  }
  // ================= layer 3: N=256, M=64, FOUT=64, batch-major out =================
  {
    constexpr size_t S = (size_t)256 * 1024;
    const float4* X34 = (const float4*)X3;
    cheb_step_nm<256, 256><<<dim3(256), blk, 0, stream>>>(
        X34, X34, ec3, (float4*)T, cI, 0.f);
    cheb_step_nm<256, 256><<<dim3(256), blk, 0, stream>>>(
        (const float4*)T, X34, ec3, (float4*)(T + S), cS, -1.f);
    cheb_step_nm<256, 256><<<dim3(256), blk, 0, stream>>>(
        (const float4*)(T + S), (const float4*)T, ec3, (float4*)(T + 2 * S), cS, -1.f);
    cheb_step_nm<256, 256><<<dim3(256), blk, 0, stream>>>(
        (const float4*)(T + 2 * S), (const float4*)(T + S), ec3, (float4*)(T + 3 * S), cS, -1.f);
    cheb_step_nm<256, 256><<<dim3(256), blk, 0, stream>>>(
        (const float4*)(T + 3 * S), (const float4*)(T + 2 * S), ec3, (float4*)(T + 4 * S), cS, -1.f);
    pool_conv_v32<256, 64, 64, true><<<dim3(128), blk, 0, stream>>>(
        X3, T, W3, b3, pc3, pv3, X4);
  }
  // ================= head =================
  encoder_partial<<<dim3(32, 16), blk, 0, stream>>>(X4, encW, P);
  encoder_reduce_cls<<<dim3(32), dim3(128), 0, stream>>>(P, encB, clsW, clsB, out);
}

// Round 6
// 338.836 us; speedup vs baseline: 1.3549x; 1.0709x over previous
//
#include <hip/hip_runtime.h>
#include <cstddef>
#include <cstdint>

#define BATCH 32

// All intermediates are NODE-MAJOR: X[n][b][f]  (addr = (n*32 + b)*F + f).
// Workspace (floats):
//   Xt : 1,572,864   (transposed input, [16384][32][3])
//   T  : 20,971,520  (T1..T5; max slice = layer1: 4096*32*32 = 4,194,304)
//   X1 : 4,194,304   ([4096][32][32])
//   X2 : 1,048,576   ([1024][32][32])
//   X3 : 262,144     ([256][32][32])
//   X4 : 131,072     ([32][4096] BATCH-major for encoder)
//   P  : 65,536      (encoder split-K partials)

__device__ __forceinline__ void fma4(float4& a, float s, const float4& w) {
  a.x += s * w.x; a.y += s * w.y; a.z += s * w.z; a.w += s * w.w;
}
__device__ __forceinline__ float4 relu4(const float4& a) {
  return make_float4(fmaxf(a.x, 0.f), fmaxf(a.y, 0.f), fmaxf(a.z, 0.f), fmaxf(a.w, 0.f));
}

// ---------------- transpose x[b][n][3] -> Xt[n][b][3] ----------------
__global__ void __launch_bounds__(256) transpose_x(
    const float* __restrict__ x, float* __restrict__ xt)
{
  int t = blockIdx.x * 256 + threadIdx.x;     // n*96 + b*3 + f
  int n = t / 96;
  int r = t % 96;
  int b = r / 3;
  int f = r - b * 3;
  xt[t] = x[((size_t)b * 16384 + n) * 3 + f];
}

// ---------------- node-major Cheb step (layer 0 only) ----------------
// out[n][r] = coef * sum_{d<6} in[ec[n,d]][r] + beta * pp[n][r]
template<int N, int R4>
__global__ void __launch_bounds__(256) cheb_step_nm(
    const float4* __restrict__ Tin, const float4* __restrict__ Tpp,
    const int* __restrict__ ec, float4* __restrict__ Tout,
    float coef, float beta)
{
  int idx = blockIdx.x * 256 + threadIdx.x;   // exact grid: N*R4 threads
  int n = idx / R4;
  int r = idx % R4;
  const int* e = ec + n * 6;
  float4 s = make_float4(0.f, 0.f, 0.f, 0.f);
#pragma unroll
  for (int d = 0; d < 6; ++d) {
    float4 v = Tin[(size_t)e[d] * R4 + r];
    s.x += v.x; s.y += v.y; s.z += v.z; s.w += v.w;
  }
  float4 p = Tpp[idx];
  float4 o;
  o.x = coef * s.x + beta * p.x;
  o.y = coef * s.y + beta * p.y;
  o.z = coef * s.z + beta * p.z;
  o.w = coef * s.w + beta * p.w;
  Tout[idx] = o;
}

// ---------------- LDS-resident Chebyshev recurrence (layers 1-3) ----------------
// Block = (b, f-slab of FS). Holds the full node column-set in LDS, runs all
// 5 steps internally (2-buffer in-place trick: T_{k+1} overwrites T_{k-1}),
// streams each T_k slab to global (node-major) for the pool_conv consumer.
template<int N, int F, int FS, int THREADS>
__global__ void __launch_bounds__(THREADS) cheb_recur_lds(
    const float* __restrict__ X,    // node-major [N][32][F]
    const int* __restrict__ ec,     // [N][6]
    float* __restrict__ T)          // 5 slices, node-major
{
  __shared__ float Abuf[N * FS];
  __shared__ float Bbuf[N * FS];
  const float cI = -1.0f / 6.0f;
  const float cS = -1.0f / 3.0f;
  const int b = blockIdx.x & 31;
  const int fbase = (blockIdx.x >> 5) * FS;
  constexpr size_t SL = (size_t)N * 32 * F;    // slice stride (floats)
  // load T0 slab
  for (int n = threadIdx.x; n < N; n += THREADS) {
    const float* src = X + ((size_t)n * 32 + b) * F + fbase;
#pragma unroll
    for (int f = 0; f < FS; ++f) Abuf[n * FS + f] = src[f];
  }
  __syncthreads();
  // T1 = cI * G(T0)
  for (int n = threadIdx.x; n < N; n += THREADS) {
    const int* e = ec + n * 6;
    float s[FS];
#pragma unroll
    for (int f = 0; f < FS; ++f) s[f] = 0.f;
#pragma unroll
    for (int d = 0; d < 6; ++d) {
      int c = e[d];
#pragma unroll
      for (int f = 0; f < FS; ++f) s[f] += Abuf[c * FS + f];
    }
    float* dst = T + ((size_t)n * 32 + b) * F + fbase;
#pragma unroll
    for (int f = 0; f < FS; ++f) {
      float v = cI * s[f];
      Bbuf[n * FS + f] = v;
      dst[f] = v;
    }
  }
  __syncthreads();
  // T_{k} = cS * G(T_{k-1}) - T_{k-2}, k = 2..5, in-place into prev buffer
  float* cur = Bbuf;
  float* prev = Abuf;
#pragma unroll 1
  for (int k = 2; k <= 5; ++k) {
    float* Tk = T + (size_t)(k - 1) * SL;
    for (int n = threadIdx.x; n < N; n += THREADS) {
      const int* e = ec + n * 6;
      float s[FS];
#pragma unroll
      for (int f = 0; f < FS; ++f) s[f] = 0.f;
#pragma unroll
      for (int d = 0; d < 6; ++d) {
        int c = e[d];
#pragma unroll
        for (int f = 0; f < FS; ++f) s[f] += cur[c * FS + f];
      }
      float* dst = Tk + ((size_t)n * 32 + b) * F + fbase;
#pragma unroll
      for (int f = 0; f < FS; ++f) {
        float v = cS * s[f] - prev[n * FS + f];
        prev[n * FS + f] = v;
        dst[f] = v;
      }
    }
    float* tmp = cur; cur = prev; prev = tmp;
    __syncthreads();
  }
}

// ---------------- fused pool(relu(conv)), FIN=3, materialized T1..T5 ----------------
template<int N, int M, int FOUT, bool OUT_BM>
__global__ void __launch_bounds__(256) pool_conv_f3(
    const float* __restrict__ X, const float* __restrict__ T,
    const float* __restrict__ W, const float* __restrict__ bias,
    const int* __restrict__ pc, const float* __restrict__ pv,
    float* __restrict__ out)
{
  constexpr int F4 = FOUT / 4;
  constexpr size_t SL = (size_t)N * BATCH * 3;   // slice stride (floats)
  __shared__ float Ws[6 * 3 * FOUT];
  for (int i = threadIdx.x; i < 6 * 3 * FOUT; i += 256) Ws[i] = W[i];
  __syncthreads();
  const float4* Ws4 = (const float4*)Ws;
  int t = blockIdx.x * 256 + threadIdx.x;     // exact grid: M*32*F4
  int fo4 = t % F4;
  int b   = (t / F4) % BATCH;
  int m   = t / (F4 * BATCH);
  int c0 = pc[m * 3 + 0], c1 = pc[m * 3 + 1], c2 = pc[m * 3 + 2];
  float v0 = pv[m * 3 + 0], v1 = pv[m * 3 + 1], v2 = pv[m * 3 + 2];
  float4 bi = ((const float4*)bias)[fo4];
  float4 a0 = bi, a1 = bi, a2 = bi;
#pragma unroll
  for (int k = 0; k < 6; ++k) {
    const float* base = (k == 0) ? X : (T + (size_t)(k - 1) * SL);
    const float* r0 = base + ((size_t)c0 * BATCH + b) * 3;
    const float* r1 = base + ((size_t)c1 * BATCH + b) * 3;
    const float* r2 = base + ((size_t)c2 * BATCH + b) * 3;
#pragma unroll
    for (int f = 0; f < 3; ++f) {
      float4 w = Ws4[(k * 3 + f) * F4 + fo4];
      fma4(a0, r0[f], w);
      fma4(a1, r1[f], w);
      fma4(a2, r2[f], w);
    }
  }
  a0 = relu4(a0); a1 = relu4(a1); a2 = relu4(a2);
  float4 acc;
  acc.x = v0*a0.x + v1*a1.x + v2*a2.x;
  acc.y = v0*a0.y + v1*a1.y + v2*a2.y;
  acc.z = v0*a0.z + v1*a1.z + v2*a2.z;
  acc.w = v0*a0.w + v1*a1.w + v2*a2.w;
  size_t oi = OUT_BM ? (((size_t)b * M + m) * F4 + fo4) : (((size_t)m * BATCH + b) * F4 + fo4);
  ((float4*)out)[oi] = acc;
}

// ---------------- fused pool(relu(conv)), FIN=32, materialized T1..T5 ----------------
template<int N, int M, int FOUT, bool OUT_BM>
__global__ void __launch_bounds__(256) pool_conv_v32(
    const float* __restrict__ X, const float* __restrict__ T,
    const float* __restrict__ W, const float* __restrict__ bias,
    const int* __restrict__ pc, const float* __restrict__ pv,
    float* __restrict__ out)
{
  constexpr int FIN = 32;
  constexpr int F4 = FOUT / 4;
  constexpr size_t SL4 = (size_t)N * BATCH * FIN / 4;   // slice stride (float4)
  __shared__ float Ws[6 * FIN * FOUT];                  // 24 KB or 48 KB
  for (int i = threadIdx.x; i < 6 * FIN * FOUT; i += 256) Ws[i] = W[i];
  __syncthreads();
  const float4* Ws4 = (const float4*)Ws;
  const float4* X4p = (const float4*)X;
  const float4* T4s = (const float4*)T;
  int t = blockIdx.x * 256 + threadIdx.x;     // exact grid: M*32*F4
  int fo4 = t % F4;
  int b   = (t / F4) % BATCH;
  int m   = t / (F4 * BATCH);
  int c0 = pc[m * 3 + 0], c1 = pc[m * 3 + 1], c2 = pc[m * 3 + 2];
  float v0 = pv[m * 3 + 0], v1 = pv[m * 3 + 1], v2 = pv[m * 3 + 2];
  float4 bi = ((const float4*)bias)[fo4];
  float4 a0 = bi, a1 = bi, a2 = bi;
#pragma unroll 1
  for (int k = 0; k < 6; ++k) {
    const float4* base = (k == 0) ? X4p : (T4s + (size_t)(k - 1) * SL4);
    const float4* r0 = base + ((size_t)c0 * BATCH + b) * 8;
    const float4* r1 = base + ((size_t)c1 * BATCH + b) * 8;
    const float4* r2 = base + ((size_t)c2 * BATCH + b) * 8;
#pragma unroll
    for (int fi = 0; fi < 8; ++fi) {
      float4 t0 = r0[fi], t1 = r1[fi], t2 = r2[fi];
#pragma unroll
      for (int ff = 0; ff < 4; ++ff) {
        float4 w = Ws4[((k * 32) + fi * 4 + ff) * F4 + fo4];
        fma4(a0, ((const float*)&t0)[ff], w);
        fma4(a1, ((const float*)&t1)[ff], w);
        fma4(a2, ((const float*)&t2)[ff], w);
      }
    }
  }
  a0 = relu4(a0); a1 = relu4(a1); a2 = relu4(a2);
  float4 acc;
  acc.x = v0*a0.x + v1*a1.x + v2*a2.x;
  acc.y = v0*a0.y + v1*a1.y + v2*a2.y;
  acc.z = v0*a0.z + v1*a1.z + v2*a2.z;
  acc.w = v0*a0.w + v1*a1.w + v2*a2.w;
  size_t oi = OUT_BM ? (((size_t)b * M + m) * F4 + fo4) : (((size_t)m * BATCH + b) * F4 + fo4);
  ((float4*)out)[oi] = acc;
}

// ---------------- encoder split-K partial ----------------
__global__ void __launch_bounds__(256) encoder_partial(
    const float* __restrict__ Xf, const float* __restrict__ encW,
    float* __restrict__ partial)
{
  int b  = blockIdx.x;        // 0..31
  int ks = blockIdx.y;        // 0..15
  int fo = threadIdx.x & 127;
  int half = threadIdx.x >> 7;
  const float* xr = Xf + b * 4096 + ks * 256 + half * 128;
  const float* w  = encW + (size_t)(ks * 256 + half * 128) * 128;
  float acc = 0.f;
#pragma unroll 8
  for (int i = 0; i < 128; ++i) acc += xr[i] * w[(size_t)i * 128 + fo];
  __shared__ float part[256];
  part[threadIdx.x] = acc;
  __syncthreads();
  if (half == 0) partial[(size_t)(b * 16 + ks) * 128 + fo] = part[fo] + part[128 + fo];
}

// ---------------- fused encoder-reduce + relu + classifier ----------------
__global__ void __launch_bounds__(128) encoder_reduce_cls(
    const float* __restrict__ partial, const float* __restrict__ encB,
    const float* __restrict__ clsW, const float* __restrict__ clsB,
    float* __restrict__ out)
{
  int b = blockIdx.x;           // 0..31
  int fo = threadIdx.x;         // 0..127
  float acc = encB[fo];
#pragma unroll
  for (int ks = 0; ks < 16; ++ks) acc += partial[(size_t)(b * 16 + ks) * 128 + fo];
  __shared__ float Hs[128];
  Hs[fo] = fmaxf(acc, 0.f);
  __syncthreads();
  if (fo < 10) {
    float s = clsB[fo];
#pragma unroll 4
    for (int f = 0; f < 128; ++f) s += Hs[f] * clsW[f * 10 + fo];
    out[b * 10 + fo] = s;
  }
}

extern "C" void kernel_launch(void* const* d_in, const int* in_sizes, int n_in,
                              void* d_out, int out_size, void* d_ws, size_t ws_size,
                              hipStream_t stream)
{
  const float* x   = (const float*)d_in[0];
  const int* ec0 = (const int*)d_in[2];
  const int* ec1 = (const int*)d_in[4];
  const int* ec2 = (const int*)d_in[6];
  const int* ec3 = (const int*)d_in[8];
  const int* pc0 = (const int*)d_in[10]; const float* pv0 = (const float*)d_in[11];
  const int* pc1 = (const int*)d_in[13]; const float* pv1 = (const float*)d_in[14];
  const int* pc2 = (const int*)d_in[16]; const float* pv2 = (const float*)d_in[17];
  const int* pc3 = (const int*)d_in[19]; const float* pv3 = (const float*)d_in[20];
  const float* W0 = (const float*)d_in[21]; const float* b0 = (const float*)d_in[22];
  const float* W1 = (const float*)d_in[23]; const float* b1 = (const float*)d_in[24];
  const float* W2 = (const float*)d_in[25]; const float* b2 = (const float*)d_in[26];
  const float* W3 = (const float*)d_in[27]; const float* b3 = (const float*)d_in[28];
  const float* encW = (const float*)d_in[29]; const float* encB = (const float*)d_in[30];
  const float* clsW = (const float*)d_in[31]; const float* clsB = (const float*)d_in[32];
  float* out = (float*)d_out;

  float* ws = (float*)d_ws;
  float* Xt = ws;                       // 1,572,864
  float* T  = Xt + 1572864;             // 20,971,520 (T1..T5, layer-1 sized)
  float* X1 = T  + 20971520;            // 4,194,304
  float* X2 = X1 + 4194304;             // 1,048,576
  float* X3 = X2 + 1048576;             // 262,144
  float* X4 = X3 + 262144;              // 131,072  ([32][4096])
  float* P  = X4 + 131072;              // 65,536

  const float cI = -1.0f / 6.0f;
  const float cS = -1.0f / 3.0f;
  dim3 blk(256);

  transpose_x<<<dim3(6144), blk, 0, stream>>>(x, Xt);

  // ================= layer 0: N=16384, R=96 (R4=24), M=4096 =================
  // LDS recurrence would need 2*64 KB buffers (> 64 KB static limit) -> keep
  // global 5-step chain here.
  {
    constexpr size_t S = (size_t)16384 * 96;   // slice floats
    const float4* Xt4 = (const float4*)Xt;
    cheb_step_nm<16384, 24><<<dim3(1536), blk, 0, stream>>>(
        Xt4, Xt4, ec0, (float4*)T, cI, 0.f);
    cheb_step_nm<16384, 24><<<dim3(1536), blk, 0, stream>>>(
        (const float4*)T, Xt4, ec0, (float4*)(T + S), cS, -1.f);
    cheb_step_nm<16384, 24><<<dim3(1536), blk, 0, stream>>>(
        (const float4*)(T + S), (const float4*)T, ec0, (float4*)(T + 2 * S), cS, -1.f);
    cheb_step_nm<16384, 24><<<dim3(1536), blk, 0, stream>>>(
        (const float4*)(T + 2 * S), (const float4*)(T + S), ec0, (float4*)(T + 3 * S), cS, -1.f);
    cheb_step_nm<16384, 24><<<dim3(1536), blk, 0, stream>>>(
        (const float4*)(T + 3 * S), (const float4*)(T + 2 * S), ec0, (float4*)(T + 4 * S), cS, -1.f);
    pool_conv_f3<16384, 4096, 32, false><<<dim3(4096), blk, 0, stream>>>(
        Xt, T, W0, b0, pc0, pv0, X1);
  }
  // ================= layer 1: N=4096, F=32, M=1024 =================
  // LDS-resident recurrence: FS=2, 512 blocks (32 b x 16 slabs), 64 KB LDS.
  {
    cheb_recur_lds<4096, 32, 2, 256><<<dim3(512), blk, 0, stream>>>(X1, ec1, T);
    pool_conv_v32<4096, 1024, 32, false><<<dim3(1024), blk, 0, stream>>>(
        X1, T, W1, b1, pc1, pv1, X2);
  }
  // ================= layer 2: N=1024, F=32, M=256 =================
  {
    cheb_recur_lds<1024, 32, 4, 256><<<dim3(256), blk, 0, stream>>>(X2, ec2, T);
    pool_conv_v32<1024, 256, 32, false><<<dim3(256), blk, 0, stream>>>(
        X2, T, W2, b2, pc2, pv2, X3);
  }
  // ================= layer 3: N=256, F=32, M=64, FOUT=64, batch-major out =================
  {
    cheb_recur_lds<256, 32, 8, 256><<<dim3(128), blk, 0, stream>>>(X3, ec3, T);
    pool_conv_v32<256, 64, 64, true><<<dim3(128), blk, 0, stream>>>(
        X3, T, W3, b3, pc3, pv3, X4);
  }
  // ================= head =================
  encoder_partial<<<dim3(32, 16), blk, 0, stream>>>(X4, encW, P);
  encoder_reduce_cls<<<dim3(32), dim3(128), 0, stream>>>(P, encB, clsW, clsB, out);
}

// Round 7
// 327.336 us; speedup vs baseline: 1.4025x; 1.0351x over previous
//
#include <hip/hip_runtime.h>
#include <cstddef>
#include <cstdint>

#define BATCH 32

// All intermediates are NODE-MAJOR: X[n][b][f]  (addr = (n*32 + b)*F + f).
// Workspace (floats):
//   Xt : 1,572,864   (transposed input, [16384][32][3])
//   T  : 20,971,520  (T1..T5; max slice = layer1: 4096*32*32 = 4,194,304)
//   X1 : 4,194,304   ([4096][32][32])
//   X2 : 1,048,576   ([1024][32][32])
//   X3 : 262,144     ([256][32][32])
//   X4 : 131,072     ([32][4096] BATCH-major for encoder)
//   P  : 65,536      (encoder split-K partials)

__device__ __forceinline__ void fma4(float4& a, float s, const float4& w) {
  a.x += s * w.x; a.y += s * w.y; a.z += s * w.z; a.w += s * w.w;
}
__device__ __forceinline__ float4 relu4(const float4& a) {
  return make_float4(fmaxf(a.x, 0.f), fmaxf(a.y, 0.f), fmaxf(a.z, 0.f), fmaxf(a.w, 0.f));
}

// ---------------- transpose x[b][n][3] -> Xt[n][b][3] ----------------
__global__ void __launch_bounds__(256) transpose_x(
    const float* __restrict__ x, float* __restrict__ xt)
{
  int t = blockIdx.x * 256 + threadIdx.x;     // n*96 + b*3 + f
  int n = t / 96;
  int r = t % 96;
  int b = r / 3;
  int f = r - b * 3;
  xt[t] = x[((size_t)b * 16384 + n) * 3 + f];
}

// ---------------- node-major Cheb step (layer 0 only) ----------------
template<int N, int R4>
__global__ void __launch_bounds__(256) cheb_step_nm(
    const float4* __restrict__ Tin, const float4* __restrict__ Tpp,
    const int* __restrict__ ec, float4* __restrict__ Tout,
    float coef, float beta)
{
  int idx = blockIdx.x * 256 + threadIdx.x;   // exact grid: N*R4 threads
  int n = idx / R4;
  int r = idx % R4;
  const int* e = ec + n * 6;
  float4 s = make_float4(0.f, 0.f, 0.f, 0.f);
#pragma unroll
  for (int d = 0; d < 6; ++d) {
    float4 v = Tin[(size_t)e[d] * R4 + r];
    s.x += v.x; s.y += v.y; s.z += v.z; s.w += v.w;
  }
  float4 p = Tpp[idx];
  float4 o;
  o.x = coef * s.x + beta * p.x;
  o.y = coef * s.y + beta * p.y;
  o.z = coef * s.z + beta * p.z;
  o.w = coef * s.w + beta * p.w;
  Tout[idx] = o;
}

// ---------------- LDS-resident Chebyshev recurrence v2 (layers 1-3) ----------------
// Block = (b, f-slab of FS). ONE LDS buffer holds T_{k-1} over all nodes;
// T_{k-2} and the thread's own T_{k-1} values live in registers (each node's
// slot is written only by its owner). Per step: gather (read LDS + store
// global) -> barrier -> overwrite own slots -> barrier.
template<int N, int F, int FS, int THREADS, int MINW>
__global__ void __launch_bounds__(THREADS, MINW) cheb_recur_reg(
    const float* __restrict__ X,    // node-major [N][32][F]
    const int* __restrict__ ec,     // [N][6]
    float* __restrict__ T)          // 5 slices, node-major
{
  constexpr int NPT = N / THREADS;             // nodes per thread
  __shared__ float cur[N * FS];
  const float cI = -1.0f / 6.0f;
  const float cS = -1.0f / 3.0f;
  const int b = blockIdx.x & 31;
  const int fbase = (blockIdx.x >> 5) * FS;
  constexpr size_t SL = (size_t)N * 32 * F;    // slice stride (floats)
  float prevv[NPT][FS];   // T_{k-2} at owned nodes
  float curv[NPT][FS];    // T_{k-1} at owned nodes
  // load T0 slab
#pragma unroll
  for (int i = 0; i < NPT; ++i) {
    int n = threadIdx.x + i * THREADS;
    const float* src = X + ((size_t)n * 32 + b) * F + fbase;
#pragma unroll
    for (int f = 0; f < FS; ++f) { float v = src[f]; cur[n * FS + f] = v; curv[i][f] = v; }
  }
  __syncthreads();
#pragma unroll 1
  for (int k = 1; k <= 5; ++k) {
    float newv[NPT][FS];
    float* Tk = T + (size_t)(k - 1) * SL;
#pragma unroll
    for (int i = 0; i < NPT; ++i) {
      int n = threadIdx.x + i * THREADS;
      const int* e = ec + n * 6;
      float s[FS];
#pragma unroll
      for (int f = 0; f < FS; ++f) s[f] = 0.f;
#pragma unroll
      for (int d = 0; d < 6; ++d) {
        int c = e[d];
#pragma unroll
        for (int f = 0; f < FS; ++f) s[f] += cur[c * FS + f];
      }
      float* dst = Tk + ((size_t)n * 32 + b) * F + fbase;
#pragma unroll
      for (int f = 0; f < FS; ++f) {
        float v = (k == 1) ? (cI * s[f]) : (cS * s[f] - prevv[i][f]);
        newv[i][f] = v;
        dst[f] = v;
      }
    }
    __syncthreads();   // all gathers of T_{k-1} complete
#pragma unroll
    for (int i = 0; i < NPT; ++i) {
      int n = threadIdx.x + i * THREADS;
#pragma unroll
      for (int f = 0; f < FS; ++f) {
        prevv[i][f] = curv[i][f];
        curv[i][f] = newv[i][f];
        cur[n * FS + f] = newv[i][f];
      }
    }
    __syncthreads();
  }
}

// ---------------- fused pool(relu(conv)), FIN=3, materialized T1..T5 ----------------
template<int N, int M, int FOUT, bool OUT_BM>
__global__ void __launch_bounds__(256) pool_conv_f3(
    const float* __restrict__ X, const float* __restrict__ T,
    const float* __restrict__ W, const float* __restrict__ bias,
    const int* __restrict__ pc, const float* __restrict__ pv,
    float* __restrict__ out)
{
  constexpr int F4 = FOUT / 4;
  constexpr size_t SL = (size_t)N * BATCH * 3;   // slice stride (floats)
  __shared__ float Ws[6 * 3 * FOUT];
  for (int i = threadIdx.x; i < 6 * 3 * FOUT; i += 256) Ws[i] = W[i];
  __syncthreads();
  const float4* Ws4 = (const float4*)Ws;
  int t = blockIdx.x * 256 + threadIdx.x;     // exact grid: M*32*F4
  int fo4 = t % F4;
  int b   = (t / F4) % BATCH;
  int m   = t / (F4 * BATCH);
  int c0 = pc[m * 3 + 0], c1 = pc[m * 3 + 1], c2 = pc[m * 3 + 2];
  float v0 = pv[m * 3 + 0], v1 = pv[m * 3 + 1], v2 = pv[m * 3 + 2];
  float4 bi = ((const float4*)bias)[fo4];
  float4 a0 = bi, a1 = bi, a2 = bi;
#pragma unroll
  for (int k = 0; k < 6; ++k) {
    const float* base = (k == 0) ? X : (T + (size_t)(k - 1) * SL);
    const float* r0 = base + ((size_t)c0 * BATCH + b) * 3;
    const float* r1 = base + ((size_t)c1 * BATCH + b) * 3;
    const float* r2 = base + ((size_t)c2 * BATCH + b) * 3;
#pragma unroll
    for (int f = 0; f < 3; ++f) {
      float4 w = Ws4[(k * 3 + f) * F4 + fo4];
      fma4(a0, r0[f], w);
      fma4(a1, r1[f], w);
      fma4(a2, r2[f], w);
    }
  }
  a0 = relu4(a0); a1 = relu4(a1); a2 = relu4(a2);
  float4 acc;
  acc.x = v0*a0.x + v1*a1.x + v2*a2.x;
  acc.y = v0*a0.y + v1*a1.y + v2*a2.y;
  acc.z = v0*a0.z + v1*a1.z + v2*a2.z;
  acc.w = v0*a0.w + v1*a1.w + v2*a2.w;
  size_t oi = OUT_BM ? (((size_t)b * M + m) * F4 + fo4) : (((size_t)m * BATCH + b) * F4 + fo4);
  ((float4*)out)[oi] = acc;
}

// ---------------- fused pool(relu(conv)), FIN=32, materialized T1..T5 ----------------
template<int N, int M, int FOUT, bool OUT_BM>
__global__ void __launch_bounds__(256) pool_conv_v32(
    const float* __restrict__ X, const float* __restrict__ T,
    const float* __restrict__ W, const float* __restrict__ bias,
    const int* __restrict__ pc, const float* __restrict__ pv,
    float* __restrict__ out)
{
  constexpr int FIN = 32;
  constexpr int F4 = FOUT / 4;
  constexpr size_t SL4 = (size_t)N * BATCH * FIN / 4;   // slice stride (float4)
  __shared__ float Ws[6 * FIN * FOUT];                  // 24 KB or 48 KB
  for (int i = threadIdx.x; i < 6 * FIN * FOUT; i += 256) Ws[i] = W[i];
  __syncthreads();
  const float4* Ws4 = (const float4*)Ws;
  const float4* X4p = (const float4*)X;
  const float4* T4s = (const float4*)T;
  int t = blockIdx.x * 256 + threadIdx.x;     // exact grid: M*32*F4
  int fo4 = t % F4;
  int b   = (t / F4) % BATCH;
  int m   = t / (F4 * BATCH);
  int c0 = pc[m * 3 + 0], c1 = pc[m * 3 + 1], c2 = pc[m * 3 + 2];
  float v0 = pv[m * 3 + 0], v1 = pv[m * 3 + 1], v2 = pv[m * 3 + 2];
  float4 bi = ((const float4*)bias)[fo4];
  float4 a0 = bi, a1 = bi, a2 = bi;
#pragma unroll 1
  for (int k = 0; k < 6; ++k) {
    const float4* base = (k == 0) ? X4p : (T4s + (size_t)(k - 1) * SL4);
    const float4* r0 = base + ((size_t)c0 * BATCH + b) * 8;
    const float4* r1 = base + ((size_t)c1 * BATCH + b) * 8;
    const float4* r2 = base + ((size_t)c2 * BATCH + b) * 8;
#pragma unroll
    for (int fi = 0; fi < 8; ++fi) {
      float4 t0 = r0[fi], t1 = r1[fi], t2 = r2[fi];
#pragma unroll
      for (int ff = 0; ff < 4; ++ff) {
        float4 w = Ws4[((k * 32) + fi * 4 + ff) * F4 + fo4];
        fma4(a0, ((const float*)&t0)[ff], w);
        fma4(a1, ((const float*)&t1)[ff], w);
        fma4(a2, ((const float*)&t2)[ff], w);
      }
    }
  }
  a0 = relu4(a0); a1 = relu4(a1); a2 = relu4(a2);
  float4 acc;
  acc.x = v0*a0.x + v1*a1.x + v2*a2.x;
  acc.y = v0*a0.y + v1*a1.y + v2*a2.y;
  acc.z = v0*a0.z + v1*a1.z + v2*a2.z;
  acc.w = v0*a0.w + v1*a1.w + v2*a2.w;
  size_t oi = OUT_BM ? (((size_t)b * M + m) * F4 + fo4) : (((size_t)m * BATCH + b) * F4 + fo4);
  ((float4*)out)[oi] = acc;
}

// ---------------- encoder split-K partial ----------------
__global__ void __launch_bounds__(256) encoder_partial(
    const float* __restrict__ Xf, const float* __restrict__ encW,
    float* __restrict__ partial)
{
  int b  = blockIdx.x;        // 0..31
  int ks = blockIdx.y;        // 0..15
  int fo = threadIdx.x & 127;
  int half = threadIdx.x >> 7;
  const float* xr = Xf + b * 4096 + ks * 256 + half * 128;
  const float* w  = encW + (size_t)(ks * 256 + half * 128) * 128;
  float acc = 0.f;
#pragma unroll 8
  for (int i = 0; i < 128; ++i) acc += xr[i] * w[(size_t)i * 128 + fo];
  __shared__ float part[256];
  part[threadIdx.x] = acc;
  __syncthreads();
  if (half == 0) partial[(size_t)(b * 16 + ks) * 128 + fo] = part[fo] + part[128 + fo];
}

// ---------------- fused encoder-reduce + relu + classifier ----------------
__global__ void __launch_bounds__(128) encoder_reduce_cls(
    const float* __restrict__ partial, const float* __restrict__ encB,
    const float* __restrict__ clsW, const float* __restrict__ clsB,
    float* __restrict__ out)
{
  int b = blockIdx.x;           // 0..31
  int fo = threadIdx.x;         // 0..127
  float acc = encB[fo];
#pragma unroll
  for (int ks = 0; ks < 16; ++ks) acc += partial[(size_t)(b * 16 + ks) * 128 + fo];
  __shared__ float Hs[128];
  Hs[fo] = fmaxf(acc, 0.f);
  __syncthreads();
  if (fo < 10) {
    float s = clsB[fo];
#pragma unroll 4
    for (int f = 0; f < 128; ++f) s += Hs[f] * clsW[f * 10 + fo];
    out[b * 10 + fo] = s;
  }
}

extern "C" void kernel_launch(void* const* d_in, const int* in_sizes, int n_in,
                              void* d_out, int out_size, void* d_ws, size_t ws_size,
                              hipStream_t stream)
{
  const float* x   = (const float*)d_in[0];
  const int* ec0 = (const int*)d_in[2];
  const int* ec1 = (const int*)d_in[4];
  const int* ec2 = (const int*)d_in[6];
  const int* ec3 = (const int*)d_in[8];
  const int* pc0 = (const int*)d_in[10]; const float* pv0 = (const float*)d_in[11];
  const int* pc1 = (const int*)d_in[13]; const float* pv1 = (const float*)d_in[14];
  const int* pc2 = (const int*)d_in[16]; const float* pv2 = (const float*)d_in[17];
  const int* pc3 = (const int*)d_in[19]; const float* pv3 = (const float*)d_in[20];
  const float* W0 = (const float*)d_in[21]; const float* b0 = (const float*)d_in[22];
  const float* W1 = (const float*)d_in[23]; const float* b1 = (const float*)d_in[24];
  const float* W2 = (const float*)d_in[25]; const float* b2 = (const float*)d_in[26];
  const float* W3 = (const float*)d_in[27]; const float* b3 = (const float*)d_in[28];
  const float* encW = (const float*)d_in[29]; const float* encB = (const float*)d_in[30];
  const float* clsW = (const float*)d_in[31]; const float* clsB = (const float*)d_in[32];
  float* out = (float*)d_out;

  float* ws = (float*)d_ws;
  float* Xt = ws;                       // 1,572,864
  float* T  = Xt + 1572864;             // 20,971,520 (T1..T5, layer-1 sized)
  float* X1 = T  + 20971520;            // 4,194,304
  float* X2 = X1 + 4194304;             // 1,048,576
  float* X3 = X2 + 1048576;             // 262,144
  float* X4 = X3 + 262144;              // 131,072  ([32][4096])
  float* P  = X4 + 131072;              // 65,536

  const float cI = -1.0f / 6.0f;
  const float cS = -1.0f / 3.0f;
  dim3 blk(256);

  transpose_x<<<dim3(6144), blk, 0, stream>>>(x, Xt);

  // ================= layer 0: N=16384, R=96 (R4=24), M=4096 =================
  // LDS-resident recurrence would need >=64 KB buffer with only 96 blocks of
  // parallelism -> keep the coalesced global 5-step chain.
  {
    constexpr size_t S = (size_t)16384 * 96;   // slice floats
    const float4* Xt4 = (const float4*)Xt;
    cheb_step_nm<16384, 24><<<dim3(1536), blk, 0, stream>>>(
        Xt4, Xt4, ec0, (float4*)T, cI, 0.f);
    cheb_step_nm<16384, 24><<<dim3(1536), blk, 0, stream>>>(
        (const float4*)T, Xt4, ec0, (float4*)(T + S), cS, -1.f);
    cheb_step_nm<16384, 24><<<dim3(1536), blk, 0, stream>>>(
        (const float4*)(T + S), (const float4*)T, ec0, (float4*)(T + 2 * S), cS, -1.f);
    cheb_step_nm<16384, 24><<<dim3(1536), blk, 0, stream>>>(
        (const float4*)(T + 2 * S), (const float4*)(T + S), ec0, (float4*)(T + 3 * S), cS, -1.f);
    cheb_step_nm<16384, 24><<<dim3(1536), blk, 0, stream>>>(
        (const float4*)(T + 3 * S), (const float4*)(T + 2 * S), ec0, (float4*)(T + 4 * S), cS, -1.f);
    pool_conv_f3<16384, 4096, 32, false><<<dim3(4096), blk, 0, stream>>>(
        Xt, T, W0, b0, pc0, pv0, X1);
  }
  // ================= layer 1: N=4096, F=32, M=1024 =================
  // FS=2 -> 512 blocks (32 b x 16 slabs) x 1024 thr, 32 KB LDS, 64-VGPR cap:
  // 2 blocks/CU = 32 waves/CU.
  {
    cheb_recur_reg<4096, 32, 2, 1024, 8><<<dim3(512), dim3(1024), 0, stream>>>(X1, ec1, T);
    pool_conv_v32<4096, 1024, 32, false><<<dim3(1024), blk, 0, stream>>>(
        X1, T, W1, b1, pc1, pv1, X2);
  }
  // ================= layer 2: N=1024, F=32, M=256 =================
  {
    cheb_recur_reg<1024, 32, 2, 256, 8><<<dim3(512), blk, 0, stream>>>(X2, ec2, T);
    pool_conv_v32<1024, 256, 32, false><<<dim3(256), blk, 0, stream>>>(
        X2, T, W2, b2, pc2, pv2, X3);
  }
  // ================= layer 3: N=256, F=32, M=64, FOUT=64, batch-major out =================
  {
    cheb_recur_reg<256, 32, 2, 256, 8><<<dim3(512), blk, 0, stream>>>(X3, ec3, T);
    pool_conv_v32<256, 64, 64, true><<<dim3(128), blk, 0, stream>>>(
        X3, T, W3, b3, pc3, pv3, X4);
  }
  // ================= head =================
  encoder_partial<<<dim3(32, 16), blk, 0, stream>>>(X4, encW, P);
  encoder_reduce_cls<<<dim3(32), dim3(128), 0, stream>>>(P, encB, clsW, clsB, out);
}